// Round 13
// baseline (347.026 us; speedup 1.0000x reference)
//
#include <hip/hip_runtime.h>
#include <hip/hip_bf16.h>
#include <stdint.h>

// MoE FFN, top-1 routing. x:[4,2048,1024] f32, 8 experts, 1024->4096->1024.
// R13: R9 (proven GEMM body) + split-K=2 FFN2 into f32 partials (reusing the
//      dead W1T region) + reduce kernel (bias + perm scatter).

#define D_MODEL 1024
#define D_FF    4096
#define NEXP    8
#define NTOK    8192
#define MAXT256 40

typedef __attribute__((ext_vector_type(8))) short bf16x8;
typedef __attribute__((ext_vector_type(8))) unsigned short u16x8;
typedef __attribute__((ext_vector_type(4))) unsigned short u16x4;
typedef __attribute__((ext_vector_type(4))) float f32x4;

// ---- workspace layout (bytes) ----
#define OFF_META 0u
#define OFF_TOPI 4096u
#define OFF_PERM 36864u
#define OFF_POS  69632u
#define OFF_XG   131072u                     // 8448*1024*2
#define OFF_H    17432576u                   // 8448*4096*2
#define OFF_W1T  86638592u                   // 8*4096*1024*2 (reused as FFN2 partials)
#define OFF_W2T  153747456u                  // 8*1024*4096*2

__device__ __forceinline__ unsigned short f2bf(float f) {
  unsigned int u = __builtin_bit_cast(unsigned int, f);
  unsigned int r = (u + 0x7FFFu + ((u >> 16) & 1u)) >> 16;
  return (unsigned short)r;
}

typedef const __attribute__((address_space(1))) unsigned int* gas_u32;
typedef __attribute__((address_space(3))) unsigned int* las_u32;

__device__ __forceinline__ void gload16(const void* g, void* l) {
  __builtin_amdgcn_global_load_lds((gas_u32)g, (las_u32)l, 16, 0, 0);
}

__device__ __forceinline__ int xcd_swz(int orig, int nwg) {
  int q = nwg >> 3, r = nwg & 7;
  int xcd = orig & 7, lid = orig >> 3;
  return (xcd < r ? xcd * (q + 1) : r * (q + 1) + (xcd - r) * q) + lid;
}

// ---------------- gating: one wave per token, fp64 accumulate ----------------
__global__ __launch_bounds__(256) void gate_kernel(const float* __restrict__ x,
    const float* __restrict__ gw, const float* __restrict__ gb,
    const float* __restrict__ eb, int* __restrict__ topi) {
  int wid = threadIdx.x >> 6, lane = threadIdx.x & 63;
  int t = blockIdx.x * 4 + wid;
  const float* xr = x + (size_t)t * D_MODEL;
  double p[NEXP];
#pragma unroll
  for (int e = 0; e < NEXP; ++e) p[e] = 0.0;
#pragma unroll
  for (int j = 0; j < 4; ++j) {
    int c = (lane + j * 64) * 4;
    f32x4 xv = *(const f32x4*)(xr + c);
#pragma unroll
    for (int e = 0; e < NEXP; ++e) {
      f32x4 gv = *(const f32x4*)(gw + e * D_MODEL + c);
#pragma unroll
      for (int q = 0; q < 4; ++q) p[e] += (double)xv[q] * (double)gv[q];
    }
  }
#pragma unroll
  for (int e = 0; e < NEXP; ++e) {
    for (int off = 32; off; off >>= 1) p[e] += __shfl_xor(p[e], off, 64);
  }
  if (lane == 0) {
    double best = -1e300; int bi = 0;
#pragma unroll
    for (int e = 0; e < NEXP; ++e) {
      double v = p[e] + (double)gb[e] + (double)eb[e];
      if (v > best) { best = v; bi = e; }
    }
    topi[t] = bi;
  }
}

// ---- rank kernel: 1 block, 1024 threads. counts/offsets/tilemap/pos/perm ----
__global__ __launch_bounds__(1024) void rank_kernel(const int* __restrict__ topi,
    int* __restrict__ meta, int* __restrict__ pos, int* __restrict__ perm) {
  __shared__ int hist[NEXP][1024];
  __shared__ int offs_s[NEXP + 1];
  int tid = threadIdx.x;
  int te[8], loc[NEXP], run[NEXP];
#pragma unroll
  for (int e = 0; e < NEXP; ++e) loc[e] = 0;
#pragma unroll
  for (int j = 0; j < 8; ++j) {
    te[j] = topi[tid * 8 + j];
#pragma unroll
    for (int e = 0; e < NEXP; ++e) loc[e] += (te[j] == e) ? 1 : 0;
  }
#pragma unroll
  for (int e = 0; e < NEXP; ++e) { run[e] = loc[e]; hist[e][tid] = run[e]; }
  __syncthreads();
  for (int s = 1; s < 1024; s <<= 1) {
    int v[NEXP];
#pragma unroll
    for (int e = 0; e < NEXP; ++e) v[e] = (tid >= s) ? hist[e][tid - s] : 0;
    __syncthreads();
#pragma unroll
    for (int e = 0; e < NEXP; ++e) { run[e] += v[e]; hist[e][tid] = run[e]; }
    __syncthreads();
  }
  if (tid == 1023) {
    int o = 0, nt = 0;
    for (int e = 0; e < NEXP; ++e) {
      offs_s[e] = o;
      meta[e] = run[e];
      meta[8 + e] = o;
      o += run[e];
    }
    offs_s[NEXP] = o; meta[16] = o;
    for (int e = 0; e < NEXP; ++e) {
      int ntile = (run[e] + 255) >> 8;        // 256-row m-tiles
      for (int j = 0; j < ntile; ++j) { meta[32 + nt] = e; meta[112 + nt] = j; ++nt; }
    }
    meta[25] = nt;
  }
  __syncthreads();
  int base[NEXP];
#pragma unroll
  for (int e = 0; e < NEXP; ++e) base[e] = offs_s[e] + run[e] - loc[e];
#pragma unroll
  for (int j = 0; j < 8; ++j) {
    int tok = tid * 8 + j, pj = 0;
#pragma unroll
    for (int e = 0; e < NEXP; ++e) {
      if (te[j] == e) pj = base[e];
      base[e] += (te[j] == e) ? 1 : 0;
    }
    pos[tok] = pj;
    perm[pj] = tok;
  }
}

// -------- scatter tokens into per-expert contiguous rows, f32 -> bf16 --------
__global__ __launch_bounds__(256) void scatter_kernel(const float* __restrict__ x,
    const int* __restrict__ pos, unsigned short* __restrict__ xg) {
  int t = blockIdx.x;
  int p = pos[t];
  const float* xr = x + (size_t)t * D_MODEL;
  unsigned short* orow = xg + (size_t)p * D_MODEL;
  int c = threadIdx.x * 4;
  f32x4 v = *(const f32x4*)(xr + c);
  u16x4 u;
#pragma unroll
  for (int j = 0; j < 4; ++j) u[j] = f2bf(v[j]);
  *(u16x4*)(orow + c) = u;
}

// ---- merged weight convert+transpose: [E][R][C] f32 -> [E][C][R] bf16 ----
__global__ __launch_bounds__(256) void transconv_all(
    const float* __restrict__ w1, unsigned short* __restrict__ w1t,
    const float* __restrict__ w2, unsigned short* __restrict__ w2t) {
  __shared__ float tile[64][65];
  int id = blockIdx.x;
  const float* src; unsigned short* dst; int R, C, c0, r0;
  if (id < 8192) {
    int e = id >> 10, rem = id & 1023;
    R = 1024; C = 4096;
    c0 = (rem & 63) * 64; r0 = (rem >> 6) * 64;
    src = w1 + (size_t)e * R * C; dst = w1t + (size_t)e * R * C;
  } else {
    int e = (id - 8192) >> 10, rem = (id - 8192) & 1023;
    R = 4096; C = 1024;
    c0 = (rem & 15) * 64; r0 = (rem >> 4) * 64;
    src = w2 + (size_t)e * R * C; dst = w2t + (size_t)e * R * C;
  }
  int tid = threadIdx.x;
  int rr = tid >> 4, cc4 = (tid & 15) * 4;
#pragma unroll
  for (int i = 0; i < 4; ++i) {
    f32x4 v = *(const f32x4*)(src + (size_t)(r0 + rr + i * 16) * C + c0 + cc4);
#pragma unroll
    for (int j = 0; j < 4; ++j) tile[rr + i * 16][cc4 + j] = v[j];
  }
  __syncthreads();
  int cc = tid >> 3, rr8 = (tid & 7) * 8;
#pragma unroll
  for (int i = 0; i < 2; ++i) {
    int c = cc + i * 32;
    u16x8 u;
#pragma unroll
    for (int j = 0; j < 8; ++j) u[j] = f2bf(tile[rr8 + j][c]);
    *(u16x8*)(dst + (size_t)(c0 + c) * R + r0 + rr8) = u;
  }
}

// ---------------- 8-phase 256x256 grouped GEMM (R9 proven body) -------------
// KS/K0: compute over K columns [K0, K0+KS) of KDIM-wide operands.
// FFN1: full K, bias+relu -> bf16 H. PARTIAL: f32 partial, no bias/perm.
#define SBAR() { __builtin_amdgcn_sched_barrier(0); __builtin_amdgcn_s_barrier(); __builtin_amdgcn_sched_barrier(0); }
#define WAIT_VM(N) { asm volatile("s_waitcnt vmcnt(" #N ")" ::: "memory"); __builtin_amdgcn_sched_barrier(0); }

template<int KDIM, int KS, int NDIM, int BN, bool IS_FFN1>
__global__ __launch_bounds__(512, 1) void gemm8(
    const unsigned short* __restrict__ A, const unsigned short* __restrict__ Bt,
    const float* __restrict__ bias, const int* __restrict__ meta,
    unsigned short* __restrict__ H, float* __restrict__ Part) {
  constexpr int NT = KS / 64;
  constexpr int SK = KDIM * 2;
  constexpr int NP = NDIM / BN;
  constexpr int NSPLIT = KDIM / KS;
  int ntiles = meta[25];
  int nwg = ntiles * NP * NSPLIT;
  int orig = blockIdx.x;
  if (orig >= nwg) return;
  int wid = xcd_swz(orig, nwg);
  int ks = wid / (ntiles * NP);
  int rem = wid % (ntiles * NP);
  int nb = rem / ntiles, t = rem % ntiles;   // n-outer, m-inner

  int e = meta[32 + t];
  int lm = meta[112 + t];
  int off = meta[8 + e];
  int rowsValid = meta[9 + e] - off - lm * 256;
  int m0 = off + lm * 256;

  __shared__ char lds[131072];

  int tid = threadIdx.x;
  int lane = tid & 63, wv = tid >> 6;
  int waveM = wv >> 2, waveN = wv & 3;       // 2M x 4N
  int lr = lane & 15, lg = lane >> 4;

  const char* aBase = (const char*)(A + (size_t)m0 * KDIM + ks * KS);
  const char* bBase = (const char*)(Bt + ((size_t)e * NDIM + nb * BN) * KDIM + ks * KS);

  const int o0 = tid * 16, o1 = o0 + 8192;
  const int lw0 = o0 >> 7, lw1 = o1 >> 7;
  const int co0 = (o0 & 127) ^ ((lw0 & 7) << 4);
  const int co1 = (o1 & 127) ^ ((lw1 & 7) << 4);
  const int mA0 = (lw0 >> 6) * 128 + (lw0 & 63), mA1 = (lw1 >> 6) * 128 + (lw1 & 63);
  const int nB0 = (lw0 >> 5) * 64 + (lw0 & 31), nB1 = (lw1 >> 5) * 64 + (lw1 & 31);

#define ST_A(D, R, KT) { \
    char* _d = lds + (D) * 65536 + (R) * 16384; \
    gload16(aBase + (size_t)(mA0 + (R) * 64) * SK + (KT) * 128 + co0, _d + o0); \
    gload16(aBase + (size_t)(mA1 + (R) * 64) * SK + (KT) * 128 + co1, _d + o1); }
#define ST_B(D, R, KT) { \
    char* _d = lds + (D) * 65536 + 32768 + (R) * 16384; \
    gload16(bBase + (size_t)(nB0 + (R) * 32) * SK + (KT) * 128 + co0, _d + o0); \
    gload16(bBase + (size_t)(nB1 + (R) * 32) * SK + (KT) * 128 + co1, _d + o1); }

  bf16x8 a[4][2], b0[2][2], b1[2][2];
#define LD_A(D, MH) { \
    const char* _b = lds + (D) * 65536 + (MH) * 16384; \
    _Pragma("unroll") for (int mfi = 0; mfi < 4; ++mfi) \
    _Pragma("unroll") for (int kq = 0; kq < 2; ++kq) { \
      int _o = (waveM * 64 + mfi * 16 + lr) * 128 + kq * 64 + lg * 16; \
      _o ^= ((_o >> 7) & 7) << 4; \
      a[mfi][kq] = *(const bf16x8*)(_b + _o); } }
#define LD_B(D, NH, BV) { \
    const char* _b = lds + (D) * 65536 + 32768 + (NH) * 16384; \
    _Pragma("unroll") for (int nfi = 0; nfi < 2; ++nfi) \
    _Pragma("unroll") for (int kq = 0; kq < 2; ++kq) { \
      int _o = (waveN * 32 + nfi * 16 + lr) * 128 + kq * 64 + lg * 16; \
      _o ^= ((_o >> 7) & 7) << 4; \
      BV[nfi][kq] = *(const bf16x8*)(_b + _o); } }

  f32x4 acc[8][4];
#pragma unroll
  for (int i = 0; i < 8; ++i)
#pragma unroll
    for (int j = 0; j < 4; ++j) acc[i][j] = (f32x4){0.f, 0.f, 0.f, 0.f};

#define MM(MH, NH, BV) { \
    __builtin_amdgcn_s_setprio(1); \
    _Pragma("unroll") for (int mfi = 0; mfi < 4; ++mfi) \
    _Pragma("unroll") for (int nfi = 0; nfi < 2; ++nfi) \
    _Pragma("unroll") for (int kq = 0; kq < 2; ++kq) \
      acc[(MH) * 4 + mfi][(NH) * 2 + nfi] = __builtin_amdgcn_mfma_f32_16x16x32_bf16( \
          a[mfi][kq], BV[nfi][kq], acc[(MH) * 4 + mfi][(NH) * 2 + nfi], 0, 0, 0); \
    __builtin_amdgcn_s_setprio(0); }

  {
    int k1 = NT > 1 ? 1 : 0;
    ST_A(0, 0, 0); ST_B(0, 1, 0); ST_A(0, 1, 0); ST_B(0, 0, 0);
    ST_A(1, 0, k1); ST_B(1, 1, k1); ST_A(1, 1, k1);
  }
  WAIT_VM(6); SBAR();

  for (int T = 0; T < NT; ++T) {
    int d = T & 1, dn = d ^ 1;
    int tp1 = T + 1 < NT ? T + 1 : T;
    int tp2 = T + 2 < NT ? T + 2 : T;
    LD_A(d, 0); LD_B(d, 0, b0);
    ST_B(dn, 0, tp1);
    SBAR();
    MM(0, 0, b0);
    SBAR();
    LD_B(d, 1, b1);
    ST_A(d, 0, tp2);
    SBAR();
    MM(0, 1, b1);
    SBAR();
    LD_A(d, 1);
    ST_B(d, 1, tp2);
    SBAR();
    MM(1, 1, b1);
    SBAR();
    ST_A(d, 1, tp2);
    SBAR();
    MM(1, 0, b0);
    WAIT_VM(6);
    SBAR();
  }
  asm volatile("s_waitcnt vmcnt(0)" ::: "memory");

  // epilogue: C/D map col=lane&15, row=(lane>>4)*4+reg
  int cb = nb * BN + waveN * (BN / 4);
#pragma unroll
  for (int mf = 0; mf < 8; ++mf) {
#pragma unroll
    for (int rg = 0; rg < 4; ++rg) {
      int rowt = waveM * 128 + mf * 16 + lg * 4 + rg;
      if (rowt >= rowsValid) continue;
      if (IS_FFN1) {
        size_t ro = (size_t)(m0 + rowt) * NDIM;
#pragma unroll
        for (int nf = 0; nf < BN / 64; ++nf) {
          int col = cb + nf * 16 + lr;
          float v = acc[mf][nf][rg] + bias[e * NDIM + col];
          H[ro + col] = f2bf(fmaxf(v, 0.f));
        }
      } else {
        size_t ro = ((size_t)ks * NTOK + (m0 + rowt)) * NDIM;
#pragma unroll
        for (int nf = 0; nf < BN / 64; ++nf) {
          int col = cb + nf * 16 + lr;
          Part[ro + col] = acc[mf][nf][rg];
        }
      }
    }
  }
#undef ST_A
#undef ST_B
#undef LD_A
#undef LD_B
#undef MM
}

// ---- reduce: out[tok] = part0[pos[tok]] + part1[pos[tok]] + b2[topi[tok]] ----
__global__ __launch_bounds__(256) void reduce_kernel(
    const float* __restrict__ part, const int* __restrict__ pos,
    const int* __restrict__ topi, const float* __restrict__ b2,
    float* __restrict__ out) {
  int tok = blockIdx.x;
  int p = pos[tok];
  int e = topi[tok];
  int c = threadIdx.x * 4;
  f32x4 a0 = *(const f32x4*)(part + (size_t)p * D_MODEL + c);
  f32x4 a1 = *(const f32x4*)(part + ((size_t)NTOK + p) * D_MODEL + c);
  f32x4 bb = *(const f32x4*)(b2 + e * D_MODEL + c);
  f32x4 r;
#pragma unroll
  for (int j = 0; j < 4; ++j) r[j] = a0[j] + a1[j] + bb[j];
  *(f32x4*)(out + (size_t)tok * D_MODEL + c) = r;
}

extern "C" void kernel_launch(void* const* d_in, const int* in_sizes, int n_in,
                              void* d_out, int out_size, void* d_ws, size_t ws_size,
                              hipStream_t stream) {
  const float* x  = (const float*)d_in[0];
  const float* gw = (const float*)d_in[1];
  const float* gb = (const float*)d_in[2];
  const float* eb = (const float*)d_in[3];
  const float* w1 = (const float*)d_in[4];
  const float* b1 = (const float*)d_in[5];
  const float* w2 = (const float*)d_in[6];
  const float* b2 = (const float*)d_in[7];
  float* out = (float*)d_out;

  char* ws = (char*)d_ws;
  int* meta = (int*)(ws + OFF_META);
  int* topi = (int*)(ws + OFF_TOPI);
  int* perm = (int*)(ws + OFF_PERM);
  int* pos  = (int*)(ws + OFF_POS);
  unsigned short* xg  = (unsigned short*)(ws + OFF_XG);
  unsigned short* h   = (unsigned short*)(ws + OFF_H);
  unsigned short* w1t = (unsigned short*)(ws + OFF_W1T);
  float*          part = (float*)(ws + OFF_W1T);   // W1T dead after FFN1
  unsigned short* w2t = (unsigned short*)(ws + OFF_W2T);

  hipLaunchKernelGGL(gate_kernel, dim3(NTOK / 4), dim3(256), 0, stream, x, gw, gb, eb, topi);
  hipLaunchKernelGGL(rank_kernel, dim3(1), dim3(1024), 0, stream, topi, meta, pos, perm);
  hipLaunchKernelGGL(scatter_kernel, dim3(NTOK), dim3(256), 0, stream, x, pos, xg);
  hipLaunchKernelGGL(transconv_all, dim3(16384), dim3(256), 0, stream, w1, w1t, w2, w2t);
  // FFN1: full K=1024, 256x256 tiles, bias+relu -> bf16 H
  hipLaunchKernelGGL((gemm8<D_MODEL, D_MODEL, D_FF, 256, true>),
                     dim3(MAXT256 * (D_FF / 256)), dim3(512), 0, stream,
                     xg, w1t, b1, meta, h, nullptr);
  // FFN2: split-K=2 (K slices of 2048), 256x256 tiles -> f32 partials
  hipLaunchKernelGGL((gemm8<D_FF, D_FF / 2, D_MODEL, 256, false>),
                     dim3(MAXT256 * (D_MODEL / 256) * 2), dim3(512), 0, stream,
                     h, w2t, nullptr, meta, nullptr, part);
  hipLaunchKernelGGL(reduce_kernel, dim3(NTOK), dim3(256), 0, stream,
                     part, pos, topi, b2, out);
}